// Round 1
// baseline (4815.430 us; speedup 1.0000x reference)
//
#include <hip/hip_runtime.h>

#define NN 100000
#define NE 1600000
#define DIM 64
#define NG 64

// ---------------- degree / norm precompute ----------------
__global__ void k_init_deg(float* deg, int n) {
    int i = blockIdx.x * blockDim.x + threadIdx.x;
    if (i < n) deg[i] = 1.0f;  // self-loop weight
}

__global__ void k_deg_accum(const int* __restrict__ col, const float* __restrict__ ew,
                            float* deg, int E) {
    int e = blockIdx.x * blockDim.x + threadIdx.x;
    if (e < E) atomicAdd(&deg[col[e]], ew[e]);
}

__global__ void k_dinv(float* deg, int n) {
    int i = blockIdx.x * blockDim.x + threadIdx.x;
    if (i < n) deg[i] = rsqrtf(deg[i]);  // deg >= 1 always
}

__global__ void k_norm(const int* __restrict__ row, const int* __restrict__ col,
                       const float* __restrict__ ew, const float* __restrict__ dinv,
                       float* __restrict__ nrm, int E) {
    int e = blockIdx.x * blockDim.x + threadIdx.x;
    if (e < E) nrm[e] = dinv[row[e]] * ew[e] * dinv[col[e]];
}

// ---------------- GEMM: out[n][64] = (relu?)in[n][64] @ W[64][64] ----------------
template <bool RELU>
__global__ __launch_bounds__(256) void k_gemm64(const float* __restrict__ in,
                                                const float* __restrict__ W,
                                                float* __restrict__ out, int n) {
    __shared__ float sW[64][64];
    __shared__ float sX[16][64];
    int tid = threadIdx.x;
    for (int i = tid; i < 64 * 64; i += 256) sW[i >> 6][i & 63] = W[i];
    int base = blockIdx.x * 16;
    for (int i = tid; i < 16 * 64; i += 256) {
        int r = i >> 6, c = i & 63;
        float v = (base + r < n) ? in[(size_t)(base + r) * DIM + c] : 0.0f;
        if (RELU) v = fmaxf(v, 0.0f);
        sX[r][c] = v;
    }
    __syncthreads();
    int d = tid & 63;
    int r0 = (tid >> 6) * 4;  // 4 rows per thread
    float a0 = 0.f, a1 = 0.f, a2 = 0.f, a3 = 0.f;
#pragma unroll
    for (int k = 0; k < 64; ++k) {
        float w = sW[k][d];
        a0 = fmaf(sX[r0 + 0][k], w, a0);
        a1 = fmaf(sX[r0 + 1][k], w, a1);
        a2 = fmaf(sX[r0 + 2][k], w, a2);
        a3 = fmaf(sX[r0 + 3][k], w, a3);
    }
    if (base + r0 + 3 < n) {
        out[(size_t)(base + r0 + 0) * DIM + d] = a0;
        out[(size_t)(base + r0 + 1) * DIM + d] = a1;
        out[(size_t)(base + r0 + 2) * DIM + d] = a2;
        out[(size_t)(base + r0 + 3) * DIM + d] = a3;
    } else {
        if (base + r0 + 0 < n) out[(size_t)(base + r0 + 0) * DIM + d] = a0;
        if (base + r0 + 1 < n) out[(size_t)(base + r0 + 1) * DIM + d] = a1;
        if (base + r0 + 2 < n) out[(size_t)(base + r0 + 2) * DIM + d] = a2;
    }
}

// ---------------- agg init: agg[n][d] = h[n][d]*dinv[n]^2 + b[d] ----------------
__global__ void k_agg_init(const float* __restrict__ h, const float* __restrict__ dinv,
                           const float* __restrict__ b, float* __restrict__ agg, int n) {
    int idx = blockIdx.x * blockDim.x + threadIdx.x;  // n*16 threads, float4 each
    if (idx >= n * 16) return;
    int node = idx >> 4, q = idx & 15;
    float di = dinv[node];
    float s = di * di;
    float4 hv = ((const float4*)h)[idx];
    float4 bv = ((const float4*)b)[q];
    float4 o;
    o.x = fmaf(hv.x, s, bv.x);
    o.y = fmaf(hv.y, s, bv.y);
    o.z = fmaf(hv.z, s, bv.z);
    o.w = fmaf(hv.w, s, bv.w);
    ((float4*)agg)[idx] = o;
}

// ---------------- edge scatter: agg[col[e]] += h[row[e]] * norm[e] ----------------
__global__ __launch_bounds__(256) void k_scatter(const int* __restrict__ row,
                                                 const int* __restrict__ col,
                                                 const float* __restrict__ nrm,
                                                 const float* __restrict__ h,
                                                 float* agg, int E) {
    int idx = blockIdx.x * blockDim.x + threadIdx.x;
    int e = idx >> 4;  // 16 threads per edge
    if (e >= E) return;
    int q = idx & 15;
    int r = row[e], c = col[e];
    float nm = nrm[e];
    float4 hv = ((const float4*)(h + (size_t)r * DIM))[q];
    float* dst = agg + (size_t)c * DIM + q * 4;
    atomicAdd(dst + 0, hv.x * nm);
    atomicAdd(dst + 1, hv.y * nm);
    atomicAdd(dst + 2, hv.z * nm);
    atomicAdd(dst + 3, hv.w * nm);
}

// ---------------- pooling ----------------
__global__ void k_pool_init(float* sums, float* cnt) {
    int i = blockIdx.x * blockDim.x + threadIdx.x;
    if (i < NG * DIM) sums[i] = 0.0f;
    if (i < NG) cnt[i] = 0.0f;
}

__global__ void k_pool(const int* __restrict__ batch, const float* __restrict__ h,
                       float* sums, float* cnt, int n) {
    int idx = blockIdx.x * blockDim.x + threadIdx.x;
    int node = idx >> 6, d = idx & 63;
    if (node >= n) return;
    int g = batch[node];
    atomicAdd(&sums[g * DIM + d], h[(size_t)node * DIM + d]);
    if (d == 0) atomicAdd(&cnt[g], 1.0f);
}

// ---------------- head: mean -> fc1(64->32) relu -> fc2(32->1) -> out(1->1) ----------
__global__ __launch_bounds__(64) void k_head(const float* __restrict__ sums,
                                             const float* __restrict__ cnt,
                                             const float* __restrict__ fc1w,
                                             const float* __restrict__ fc1b,
                                             const float* __restrict__ fc2w,
                                             const float* __restrict__ fc2b,
                                             const float* __restrict__ ow,
                                             const float* __restrict__ ob,
                                             float* __restrict__ out) {
    int g = blockIdx.x;
    int t = threadIdx.x;  // 64 threads = 1 wave
    __shared__ float gv[64];
    float c = fmaxf(cnt[g], 1.0f);
    gv[t] = sums[g * DIM + t] / c;
    __syncthreads();
    float r = 0.0f;
    if (t < 32) {
        float acc = fc1b[t];
#pragma unroll
        for (int k = 0; k < 64; ++k) acc = fmaf(gv[k], fc1w[k * 32 + t], acc);
        acc = fmaxf(acc, 0.0f);
        r = acc * fc2w[t];
    }
#pragma unroll
    for (int off = 16; off; off >>= 1) r += __shfl_down(r, off);
    if (t == 0) out[g] = (r + fc2b[0]) * ow[0] + ob[0];
}

extern "C" void kernel_launch(void* const* d_in, const int* in_sizes, int n_in,
                              void* d_out, int out_size, void* d_ws, size_t ws_size,
                              hipStream_t stream) {
    const float* x   = (const float*)d_in[0];
    const int* eidx  = (const int*)d_in[1];
    const float* ew  = (const float*)d_in[2];
    const int* batch = (const int*)d_in[3];
    const float* W0  = (const float*)d_in[4];
    const float* b0  = (const float*)d_in[5];
    const float* W1  = (const float*)d_in[6];
    const float* b1  = (const float*)d_in[7];
    const float* W2  = (const float*)d_in[8];
    const float* b2  = (const float*)d_in[9];
    const float* fc1w = (const float*)d_in[10];
    const float* fc1b = (const float*)d_in[11];
    const float* fc2w = (const float*)d_in[12];
    const float* fc2b = (const float*)d_in[13];
    const float* ow   = (const float*)d_in[14];
    const float* ob   = (const float*)d_in[15];
    float* out = (float*)d_out;

    const int* row = eidx;
    const int* col = eidx + NE;

    float* ws = (float*)d_ws;
    float* deg  = ws;                       // N floats (becomes dinv in place)
    float* nrm  = deg + NN;                 // E floats
    float* H    = nrm + NE;                 // N*64
    float* O    = H + (size_t)NN * DIM;     // N*64
    float* sums = O + (size_t)NN * DIM;     // 64*64
    float* cnt  = sums + NG * DIM;          // 64

    // degree + norm
    k_init_deg<<<(NN + 255) / 256, 256, 0, stream>>>(deg, NN);
    k_deg_accum<<<(NE + 255) / 256, 256, 0, stream>>>(col, ew, deg, NE);
    k_dinv<<<(NN + 255) / 256, 256, 0, stream>>>(deg, NN);
    k_norm<<<(NE + 255) / 256, 256, 0, stream>>>(row, col, ew, deg, nrm, NE);

    int gemm_blocks = (NN + 15) / 16;
    int aggi_blocks = (NN * 16 + 255) / 256;
    int scat_blocks = (int)(((size_t)NE * 16 + 255) / 256);

    // layer 0: x -> O
    k_gemm64<false><<<gemm_blocks, 256, 0, stream>>>(x, W0, H, NN);
    k_agg_init<<<aggi_blocks, 256, 0, stream>>>(H, deg, b0, O, NN);
    k_scatter<<<scat_blocks, 256, 0, stream>>>(row, col, nrm, H, O, NE);

    // layer 1: relu(O) -> O
    k_gemm64<true><<<gemm_blocks, 256, 0, stream>>>(O, W1, H, NN);
    k_agg_init<<<aggi_blocks, 256, 0, stream>>>(H, deg, b1, O, NN);
    k_scatter<<<scat_blocks, 256, 0, stream>>>(row, col, nrm, H, O, NE);

    // layer 2: relu(O) -> O (no relu after)
    k_gemm64<true><<<gemm_blocks, 256, 0, stream>>>(O, W2, H, NN);
    k_agg_init<<<aggi_blocks, 256, 0, stream>>>(H, deg, b2, O, NN);
    k_scatter<<<scat_blocks, 256, 0, stream>>>(row, col, nrm, H, O, NE);

    // pooling + head
    k_pool_init<<<(NG * DIM + 255) / 256, 256, 0, stream>>>(sums, cnt);
    k_pool<<<(NN * 64 + 255) / 256, 256, 0, stream>>>(batch, O, sums, cnt, NN);
    k_head<<<NG, 64, 0, stream>>>(sums, cnt, fc1w, fc1b, fc2w, fc2b, ow, ob, out);
}

// Round 2
// 862.893 us; speedup vs baseline: 5.5806x; 5.5806x over previous
//
#include <hip/hip_runtime.h>

#define NN 100000
#define NE 1600000
#define DIM 64
#define NG 64

#define SCAN_CHUNK 1024
#define NB_SCAN ((NN + SCAN_CHUNK - 1) / SCAN_CHUNK)

// ---------------- degree / norm precompute ----------------
__global__ void k_init_deg(float* deg, int n) {
    int i = blockIdx.x * blockDim.x + threadIdx.x;
    if (i < n) deg[i] = 1.0f;  // self-loop weight
}

__global__ void k_deg_accum(const int* __restrict__ col, const float* __restrict__ ew,
                            float* deg, int E) {
    int e = blockIdx.x * blockDim.x + threadIdx.x;
    if (e < E) atomicAdd(&deg[col[e]], ew[e]);
}

__global__ void k_dinv(float* deg, int n) {
    int i = blockIdx.x * blockDim.x + threadIdx.x;
    if (i < n) deg[i] = rsqrtf(deg[i]);  // deg >= 1 always
}

// ---------------- CSR build ----------------
__global__ void k_zero_int(int* p, int n) {
    int i = blockIdx.x * blockDim.x + threadIdx.x;
    if (i < n) p[i] = 0;
}

__global__ void k_hist(const int* __restrict__ col, int* cnt, int E) {
    int e = blockIdx.x * blockDim.x + threadIdx.x;
    if (e < E) atomicAdd(&cnt[col[e]], 1);
}

// per-block reduce of 1024-element chunks
__global__ __launch_bounds__(256) void k_scan_reduce(const int* __restrict__ cnt,
                                                     int* __restrict__ bsum, int n) {
    __shared__ int sm[256];
    int t = threadIdx.x;
    int base = blockIdx.x * SCAN_CHUNK + t * 4;
    int s = 0;
#pragma unroll
    for (int i = 0; i < 4; ++i) {
        int idx = base + i;
        if (idx < n) s += cnt[idx];
    }
    sm[t] = s;
    __syncthreads();
    for (int off = 128; off; off >>= 1) {
        if (t < off) sm[t] += sm[t + off];
        __syncthreads();
    }
    if (t == 0) bsum[blockIdx.x] = sm[0];
}

// single-thread scan of block sums (nb ~ 98, trivial)
__global__ void k_scan_bsums(int* bsum, int nb, int* rowptr, int n, int E) {
    if (threadIdx.x == 0 && blockIdx.x == 0) {
        int acc = 0;
        for (int i = 0; i < nb; ++i) {
            int v = bsum[i];
            bsum[i] = acc;
            acc += v;
        }
        rowptr[n] = E;
    }
}

__global__ __launch_bounds__(256) void k_scan_final(const int* __restrict__ cnt,
                                                    const int* __restrict__ bsum,
                                                    int* __restrict__ rowptr,
                                                    int* __restrict__ cursor, int n) {
    __shared__ int sm[256];
    int t = threadIdx.x;
    int base = blockIdx.x * SCAN_CHUNK + t * 4;
    int v[4];
    int s = 0;
#pragma unroll
    for (int i = 0; i < 4; ++i) {
        int idx = base + i;
        v[i] = (idx < n) ? cnt[idx] : 0;
        s += v[i];
    }
    sm[t] = s;
    __syncthreads();
    // Kogge-Stone inclusive scan of thread sums
    for (int off = 1; off < 256; off <<= 1) {
        int tmp = (t >= off) ? sm[t - off] : 0;
        __syncthreads();
        sm[t] += tmp;
        __syncthreads();
    }
    int run = bsum[blockIdx.x] + sm[t] - s;  // exclusive prefix for this thread
#pragma unroll
    for (int i = 0; i < 4; ++i) {
        int idx = base + i;
        if (idx < n) {
            rowptr[idx] = run;
            cursor[idx] = run;
            run += v[i];
        }
    }
}

__global__ void k_place(const int* __restrict__ row, const int* __restrict__ col,
                        const float* __restrict__ ew, const float* __restrict__ dinv,
                        int* cursor, int* __restrict__ csr_row,
                        float* __restrict__ csr_nrm, int E) {
    int e = blockIdx.x * blockDim.x + threadIdx.x;
    if (e >= E) return;
    int r = row[e], c = col[e];
    int p = atomicAdd(&cursor[c], 1);
    csr_row[p] = r;
    csr_nrm[p] = dinv[r] * ew[e] * dinv[c];
}

// ---------------- GEMM: out[n][64] = (relu?)in[n][64] @ W[64][64] ----------------
template <bool RELU>
__global__ __launch_bounds__(256) void k_gemm64(const float* __restrict__ in,
                                                const float* __restrict__ W,
                                                float* __restrict__ out, int n) {
    __shared__ float sW[64][64];
    __shared__ float sX[16][64];
    int tid = threadIdx.x;
    for (int i = tid; i < 64 * 64; i += 256) sW[i >> 6][i & 63] = W[i];
    int base = blockIdx.x * 16;
    for (int i = tid; i < 16 * 64; i += 256) {
        int r = i >> 6, c = i & 63;
        float v = (base + r < n) ? in[(size_t)(base + r) * DIM + c] : 0.0f;
        if (RELU) v = fmaxf(v, 0.0f);
        sX[r][c] = v;
    }
    __syncthreads();
    int d = tid & 63;
    int r0 = (tid >> 6) * 4;  // 4 rows per thread
    float a0 = 0.f, a1 = 0.f, a2 = 0.f, a3 = 0.f;
#pragma unroll
    for (int k = 0; k < 64; ++k) {
        float w = sW[k][d];
        a0 = fmaf(sX[r0 + 0][k], w, a0);
        a1 = fmaf(sX[r0 + 1][k], w, a1);
        a2 = fmaf(sX[r0 + 2][k], w, a2);
        a3 = fmaf(sX[r0 + 3][k], w, a3);
    }
    if (base + r0 + 3 < n) {
        out[(size_t)(base + r0 + 0) * DIM + d] = a0;
        out[(size_t)(base + r0 + 1) * DIM + d] = a1;
        out[(size_t)(base + r0 + 2) * DIM + d] = a2;
        out[(size_t)(base + r0 + 3) * DIM + d] = a3;
    } else {
        if (base + r0 + 0 < n) out[(size_t)(base + r0 + 0) * DIM + d] = a0;
        if (base + r0 + 1 < n) out[(size_t)(base + r0 + 1) * DIM + d] = a1;
        if (base + r0 + 2 < n) out[(size_t)(base + r0 + 2) * DIM + d] = a2;
    }
}

// ---------------- gather: out[n][d] = b[d] + h[n][d]*dinv^2 + sum_e h[src][d]*nrm ----
__global__ __launch_bounds__(256) void k_gather(const int* __restrict__ rowptr,
                                                const int* __restrict__ csr_row,
                                                const float* __restrict__ csr_nrm,
                                                const float* __restrict__ h,
                                                const float* __restrict__ dinv,
                                                const float* __restrict__ b,
                                                float* __restrict__ out, int n) {
    int node = blockIdx.x * 4 + (threadIdx.x >> 6);
    if (node >= n) return;
    int d = threadIdx.x & 63;
    int e = rowptr[node], end = rowptr[node + 1];
    float di = dinv[node];
    float acc = fmaf(h[(size_t)node * DIM + d], di * di, b[d]);
    // software-pipelined gather: prefetch (row, nrm) one iteration ahead
    int r = 0;
    float nm = 0.f;
    if (e < end) {
        r = csr_row[e];
        nm = csr_nrm[e];
    }
    while (e < end) {
        int en = e + 1;
        int r2 = 0;
        float nm2 = 0.f;
        if (en < end) {
            r2 = csr_row[en];
            nm2 = csr_nrm[en];
        }
        acc = fmaf(h[(size_t)r * DIM + d], nm, acc);
        r = r2;
        nm = nm2;
        e = en;
    }
    out[(size_t)node * DIM + d] = acc;
}

// ---------------- pooling (batch is sorted -> run-length segmented sum) ----------
__global__ void k_pool_init(float* sums, float* cnt) {
    int i = blockIdx.x * blockDim.x + threadIdx.x;
    if (i < NG * DIM) sums[i] = 0.0f;
    if (i < NG) cnt[i] = 0.0f;
}

#define PCH 256
__global__ __launch_bounds__(256) void k_pool(const int* __restrict__ batch,
                                              const float* __restrict__ h,
                                              float* sums, float* cnt, int n) {
    int t = threadIdx.x;
    int d = t & 63, s = t >> 6;
    int base = blockIdx.x * PCH;
    float acc = 0.f;
    int gcur = -1, cntv = 0;
    for (int i = s; i < PCH; i += 4) {
        int node = base + i;
        if (node >= n) break;
        int g = batch[node];
        if (g != gcur) {
            if (gcur >= 0) {
                atomicAdd(&sums[gcur * DIM + d], acc);
                if (d == 0) atomicAdd(&cnt[gcur], (float)cntv);
            }
            gcur = g;
            acc = 0.f;
            cntv = 0;
        }
        acc += h[(size_t)node * DIM + d];
        cntv++;
    }
    if (gcur >= 0) {
        atomicAdd(&sums[gcur * DIM + d], acc);
        if (d == 0) atomicAdd(&cnt[gcur], (float)cntv);
    }
}

// ---------------- head: mean -> fc1(64->32) relu -> fc2(32->1) -> out(1->1) ----------
__global__ __launch_bounds__(64) void k_head(const float* __restrict__ sums,
                                             const float* __restrict__ cnt,
                                             const float* __restrict__ fc1w,
                                             const float* __restrict__ fc1b,
                                             const float* __restrict__ fc2w,
                                             const float* __restrict__ fc2b,
                                             const float* __restrict__ ow,
                                             const float* __restrict__ ob,
                                             float* __restrict__ out) {
    int g = blockIdx.x;
    int t = threadIdx.x;  // 64 threads = 1 wave
    __shared__ float gv[64];
    float c = fmaxf(cnt[g], 1.0f);
    gv[t] = sums[g * DIM + t] / c;
    __syncthreads();
    float r = 0.0f;
    if (t < 32) {
        float acc = fc1b[t];
#pragma unroll
        for (int k = 0; k < 64; ++k) acc = fmaf(gv[k], fc1w[k * 32 + t], acc);
        acc = fmaxf(acc, 0.0f);
        r = acc * fc2w[t];
    }
#pragma unroll
    for (int off = 16; off; off >>= 1) r += __shfl_down(r, off);
    if (t == 0) out[g] = (r + fc2b[0]) * ow[0] + ob[0];
}

extern "C" void kernel_launch(void* const* d_in, const int* in_sizes, int n_in,
                              void* d_out, int out_size, void* d_ws, size_t ws_size,
                              hipStream_t stream) {
    const float* x   = (const float*)d_in[0];
    const int* eidx  = (const int*)d_in[1];
    const float* ew  = (const float*)d_in[2];
    const int* batch = (const int*)d_in[3];
    const float* W0  = (const float*)d_in[4];
    const float* b0  = (const float*)d_in[5];
    const float* W1  = (const float*)d_in[6];
    const float* b1  = (const float*)d_in[7];
    const float* W2  = (const float*)d_in[8];
    const float* b2  = (const float*)d_in[9];
    const float* fc1w = (const float*)d_in[10];
    const float* fc1b = (const float*)d_in[11];
    const float* fc2w = (const float*)d_in[12];
    const float* fc2b = (const float*)d_in[13];
    const float* ow   = (const float*)d_in[14];
    const float* ob   = (const float*)d_in[15];
    float* out = (float*)d_out;

    const int* row = eidx;
    const int* col = eidx + NE;

    // workspace layout
    char* ws = (char*)d_ws;
    float* dinv    = (float*)ws;                      ws += sizeof(float) * NN;
    int*   cnt_i   = (int*)ws;                        ws += sizeof(int) * NN;
    int*   rowptr  = (int*)ws;                        ws += sizeof(int) * (NN + 1);
    int*   cursor  = (int*)ws;                        ws += sizeof(int) * NN;
    int*   bsum    = (int*)ws;                        ws += sizeof(int) * (NB_SCAN + 8);
    int*   csr_row = (int*)ws;                        ws += sizeof(int) * NE;
    float* csr_nrm = (float*)ws;                      ws += sizeof(float) * NE;
    float* H       = (float*)ws;                      ws += sizeof(float) * (size_t)NN * DIM;
    float* O       = (float*)ws;                      ws += sizeof(float) * (size_t)NN * DIM;
    float* sums    = (float*)ws;                      ws += sizeof(float) * NG * DIM;
    float* cntf    = (float*)ws;

    const int TB = 256;
    int nblk_n = (NN + TB - 1) / TB;
    int nblk_e = (NE + TB - 1) / TB;

    // degree -> dinv
    k_init_deg<<<nblk_n, TB, 0, stream>>>(dinv, NN);
    k_deg_accum<<<nblk_e, TB, 0, stream>>>(col, ew, dinv, NE);
    k_dinv<<<nblk_n, TB, 0, stream>>>(dinv, NN);

    // CSR build (col-major adjacency)
    k_zero_int<<<nblk_n, TB, 0, stream>>>(cnt_i, NN);
    k_hist<<<nblk_e, TB, 0, stream>>>(col, cnt_i, NE);
    k_scan_reduce<<<NB_SCAN, 256, 0, stream>>>(cnt_i, bsum, NN);
    k_scan_bsums<<<1, 64, 0, stream>>>(bsum, NB_SCAN, rowptr, NN, NE);
    k_scan_final<<<NB_SCAN, 256, 0, stream>>>(cnt_i, bsum, rowptr, cursor, NN);
    k_place<<<nblk_e, TB, 0, stream>>>(row, col, ew, dinv, cursor, csr_row, csr_nrm, NE);

    int gemm_blocks = (NN + 15) / 16;
    int gath_blocks = (NN + 3) / 4;

    // layer 0: x -> H -> O
    k_gemm64<false><<<gemm_blocks, 256, 0, stream>>>(x, W0, H, NN);
    k_gather<<<gath_blocks, 256, 0, stream>>>(rowptr, csr_row, csr_nrm, H, dinv, b0, O, NN);

    // layer 1: relu(O) @ W1 -> H -> O
    k_gemm64<true><<<gemm_blocks, 256, 0, stream>>>(O, W1, H, NN);
    k_gather<<<gath_blocks, 256, 0, stream>>>(rowptr, csr_row, csr_nrm, H, dinv, b1, O, NN);

    // layer 2
    k_gemm64<true><<<gemm_blocks, 256, 0, stream>>>(O, W2, H, NN);
    k_gather<<<gath_blocks, 256, 0, stream>>>(rowptr, csr_row, csr_nrm, H, dinv, b2, O, NN);

    // pooling + head
    k_pool_init<<<(NG * DIM + TB - 1) / TB, TB, 0, stream>>>(sums, cntf);
    k_pool<<<(NN + PCH - 1) / PCH, 256, 0, stream>>>(batch, O, sums, cntf, NN);
    k_head<<<NG, 64, 0, stream>>>(sums, cntf, fc1w, fc1b, fc2w, fc2b, ow, ob, out);
}

// Round 3
// 751.368 us; speedup vs baseline: 6.4089x; 1.1484x over previous
//
#include <hip/hip_runtime.h>
#include <hip/hip_bf16.h>

#define NN 100000
#define NE 1600000
#define DIM 64
#define NG 64

#define SCAN_CHUNK 1024
#define NB_SCAN ((NN + SCAN_CHUNK - 1) / SCAN_CHUNK)

// ---------------- init: deg=1 (self-loop), cnt=0 ----------------
__global__ void k_init(float* deg, int* cnt, int n) {
    int i = blockIdx.x * blockDim.x + threadIdx.x;
    if (i < n) {
        deg[i] = 1.0f;
        cnt[i] = 0;
    }
}

// ---------------- fused edge pass: weighted degree + histogram ----------------
__global__ void k_edge_pass(const int* __restrict__ col, const float* __restrict__ ew,
                            float* deg, int* cnt, int E) {
    int e = blockIdx.x * blockDim.x + threadIdx.x;
    if (e < E) {
        int c = col[e];
        atomicAdd(&deg[c], ew[e]);
        atomicAdd(&cnt[c], 1);
    }
}

__global__ void k_dinv(float* deg, int n) {
    int i = blockIdx.x * blockDim.x + threadIdx.x;
    if (i < n) deg[i] = rsqrtf(deg[i]);  // deg >= 1 always
}

// ---------------- CSR build: scan ----------------
__global__ __launch_bounds__(256) void k_scan_reduce(const int* __restrict__ cnt,
                                                     int* __restrict__ bsum, int n) {
    __shared__ int sm[256];
    int t = threadIdx.x;
    int base = blockIdx.x * SCAN_CHUNK + t * 4;
    int s = 0;
#pragma unroll
    for (int i = 0; i < 4; ++i) {
        int idx = base + i;
        if (idx < n) s += cnt[idx];
    }
    sm[t] = s;
    __syncthreads();
    for (int off = 128; off; off >>= 1) {
        if (t < off) sm[t] += sm[t + off];
        __syncthreads();
    }
    if (t == 0) bsum[blockIdx.x] = sm[0];
}

__global__ void k_scan_bsums(int* bsum, int nb, int* rowptr, int n, int E) {
    if (threadIdx.x == 0 && blockIdx.x == 0) {
        int acc = 0;
        for (int i = 0; i < nb; ++i) {
            int v = bsum[i];
            bsum[i] = acc;
            acc += v;
        }
        rowptr[n] = E;
    }
}

__global__ __launch_bounds__(256) void k_scan_final(const int* __restrict__ cnt,
                                                    const int* __restrict__ bsum,
                                                    int* __restrict__ rowptr,
                                                    int* __restrict__ cursor, int n) {
    __shared__ int sm[256];
    int t = threadIdx.x;
    int base = blockIdx.x * SCAN_CHUNK + t * 4;
    int v[4];
    int s = 0;
#pragma unroll
    for (int i = 0; i < 4; ++i) {
        int idx = base + i;
        v[i] = (idx < n) ? cnt[idx] : 0;
        s += v[i];
    }
    sm[t] = s;
    __syncthreads();
    for (int off = 1; off < 256; off <<= 1) {
        int tmp = (t >= off) ? sm[t - off] : 0;
        __syncthreads();
        sm[t] += tmp;
        __syncthreads();
    }
    int run = bsum[blockIdx.x] + sm[t] - s;
#pragma unroll
    for (int i = 0; i < 4; ++i) {
        int idx = base + i;
        if (idx < n) {
            rowptr[idx] = run;
            cursor[idx] = run;
            run += v[i];
        }
    }
}

// csr record: .x = src row, .y = norm as float bits (one 8B store)
__global__ void k_place(const int* __restrict__ row, const int* __restrict__ col,
                        const float* __restrict__ ew, const float* __restrict__ dinv,
                        int* cursor, int2* __restrict__ csr, int E) {
    int e = blockIdx.x * blockDim.x + threadIdx.x;
    if (e >= E) return;
    int r = row[e], c = col[e];
    int p = atomicAdd(&cursor[c], 1);
    float nm = dinv[r] * ew[e] * dinv[c];
    csr[p] = make_int2(r, __float_as_int(nm));
}

// ---------------- GEMM: outbf16[n][64] = (relu?)in[n][64] @ W[64][64] ----------------
template <bool RELU>
__global__ __launch_bounds__(256) void k_gemm64(const float* __restrict__ in,
                                                const float* __restrict__ W,
                                                __hip_bfloat16* __restrict__ out, int n) {
    __shared__ float sW[64][64];
    __shared__ float sX[16][64];
    int tid = threadIdx.x;
    for (int i = tid; i < 64 * 64; i += 256) sW[i >> 6][i & 63] = W[i];
    int base = blockIdx.x * 16;
    for (int i = tid; i < 16 * 64; i += 256) {
        int r = i >> 6, c = i & 63;
        float v = (base + r < n) ? in[(size_t)(base + r) * DIM + c] : 0.0f;
        if (RELU) v = fmaxf(v, 0.0f);
        sX[r][c] = v;
    }
    __syncthreads();
    int d = tid & 63;
    int r0 = (tid >> 6) * 4;
    float a0 = 0.f, a1 = 0.f, a2 = 0.f, a3 = 0.f;
#pragma unroll
    for (int k = 0; k < 64; ++k) {
        float w = sW[k][d];
        a0 = fmaf(sX[r0 + 0][k], w, a0);
        a1 = fmaf(sX[r0 + 1][k], w, a1);
        a2 = fmaf(sX[r0 + 2][k], w, a2);
        a3 = fmaf(sX[r0 + 3][k], w, a3);
    }
    if (base + r0 + 0 < n) out[(size_t)(base + r0 + 0) * DIM + d] = __float2bfloat16(a0);
    if (base + r0 + 1 < n) out[(size_t)(base + r0 + 1) * DIM + d] = __float2bfloat16(a1);
    if (base + r0 + 2 < n) out[(size_t)(base + r0 + 2) * DIM + d] = __float2bfloat16(a2);
    if (base + r0 + 3 < n) out[(size_t)(base + r0 + 3) * DIM + d] = __float2bfloat16(a3);
}

// ---------------- gather: out = b + h[node]*dinv^2 + sum_e h[src]*nrm (h in bf16) ----
__global__ __launch_bounds__(256) void k_gather(const int* __restrict__ rowptr,
                                                const int2* __restrict__ csr,
                                                const __hip_bfloat16* __restrict__ h,
                                                const float* __restrict__ dinv,
                                                const float* __restrict__ b,
                                                float* __restrict__ out, int n) {
    int node = blockIdx.x * 4 + (threadIdx.x >> 6);
    if (node >= n) return;
    int d = threadIdx.x & 63;
    int e = rowptr[node], end = rowptr[node + 1];
    float di = dinv[node];
    float acc = fmaf(__bfloat162float(h[(size_t)node * DIM + d]), di * di, b[d]);
    // 4-deep unroll: 4 independent gather loads in flight per wave
    for (; e + 4 <= end; e += 4) {
        int2 p0 = csr[e + 0];
        int2 p1 = csr[e + 1];
        int2 p2 = csr[e + 2];
        int2 p3 = csr[e + 3];
        float h0 = __bfloat162float(h[(size_t)p0.x * DIM + d]);
        float h1 = __bfloat162float(h[(size_t)p1.x * DIM + d]);
        float h2 = __bfloat162float(h[(size_t)p2.x * DIM + d]);
        float h3 = __bfloat162float(h[(size_t)p3.x * DIM + d]);
        acc = fmaf(h0, __int_as_float(p0.y), acc);
        acc = fmaf(h1, __int_as_float(p1.y), acc);
        acc = fmaf(h2, __int_as_float(p2.y), acc);
        acc = fmaf(h3, __int_as_float(p3.y), acc);
    }
    for (; e < end; ++e) {
        int2 p = csr[e];
        acc = fmaf(__bfloat162float(h[(size_t)p.x * DIM + d]), __int_as_float(p.y), acc);
    }
    out[(size_t)node * DIM + d] = acc;
}

// ---------------- pooling (batch sorted -> run-length partial sums) ----------
__global__ void k_pool_init(float* sums, float* cnt) {
    int i = blockIdx.x * blockDim.x + threadIdx.x;
    if (i < NG * DIM) sums[i] = 0.0f;
    if (i < NG) cnt[i] = 0.0f;
}

#define PCH 256
__global__ __launch_bounds__(256) void k_pool(const int* __restrict__ batch,
                                              const float* __restrict__ h,
                                              float* sums, float* cnt, int n) {
    int t = threadIdx.x;
    int d = t & 63, s = t >> 6;
    int base = blockIdx.x * PCH;
    float acc = 0.f;
    int gcur = -1, cntv = 0;
    for (int i = s; i < PCH; i += 4) {
        int node = base + i;
        if (node >= n) break;
        int g = batch[node];
        if (g != gcur) {
            if (gcur >= 0) {
                atomicAdd(&sums[gcur * DIM + d], acc);
                if (d == 0) atomicAdd(&cnt[gcur], (float)cntv);
            }
            gcur = g;
            acc = 0.f;
            cntv = 0;
        }
        acc += h[(size_t)node * DIM + d];
        cntv++;
    }
    if (gcur >= 0) {
        atomicAdd(&sums[gcur * DIM + d], acc);
        if (d == 0) atomicAdd(&cnt[gcur], (float)cntv);
    }
}

// ---------------- head ----------------
__global__ __launch_bounds__(64) void k_head(const float* __restrict__ sums,
                                             const float* __restrict__ cnt,
                                             const float* __restrict__ fc1w,
                                             const float* __restrict__ fc1b,
                                             const float* __restrict__ fc2w,
                                             const float* __restrict__ fc2b,
                                             const float* __restrict__ ow,
                                             const float* __restrict__ ob,
                                             float* __restrict__ out) {
    int g = blockIdx.x;
    int t = threadIdx.x;
    __shared__ float gv[64];
    float c = fmaxf(cnt[g], 1.0f);
    gv[t] = sums[g * DIM + t] / c;
    __syncthreads();
    float r = 0.0f;
    if (t < 32) {
        float acc = fc1b[t];
#pragma unroll
        for (int k = 0; k < 64; ++k) acc = fmaf(gv[k], fc1w[k * 32 + t], acc);
        acc = fmaxf(acc, 0.0f);
        r = acc * fc2w[t];
    }
#pragma unroll
    for (int off = 16; off; off >>= 1) r += __shfl_down(r, off);
    if (t == 0) out[g] = (r + fc2b[0]) * ow[0] + ob[0];
}

extern "C" void kernel_launch(void* const* d_in, const int* in_sizes, int n_in,
                              void* d_out, int out_size, void* d_ws, size_t ws_size,
                              hipStream_t stream) {
    const float* x   = (const float*)d_in[0];
    const int* eidx  = (const int*)d_in[1];
    const float* ew  = (const float*)d_in[2];
    const int* batch = (const int*)d_in[3];
    const float* W0  = (const float*)d_in[4];
    const float* b0  = (const float*)d_in[5];
    const float* W1  = (const float*)d_in[6];
    const float* b1  = (const float*)d_in[7];
    const float* W2  = (const float*)d_in[8];
    const float* b2  = (const float*)d_in[9];
    const float* fc1w = (const float*)d_in[10];
    const float* fc1b = (const float*)d_in[11];
    const float* fc2w = (const float*)d_in[12];
    const float* fc2b = (const float*)d_in[13];
    const float* ow   = (const float*)d_in[14];
    const float* ob   = (const float*)d_in[15];
    float* out = (float*)d_out;

    const int* row = eidx;
    const int* col = eidx + NE;

    // workspace layout (8B-aligned blocks first)
    char* ws = (char*)d_ws;
    int2* csr              = (int2*)ws;               ws += sizeof(int2) * NE;           // 12.8MB
    __hip_bfloat16* H      = (__hip_bfloat16*)ws;     ws += sizeof(__hip_bfloat16) * (size_t)NN * DIM;  // 12.8MB
    float* O               = (float*)ws;              ws += sizeof(float) * (size_t)NN * DIM;           // 25.6MB
    float* dinv            = (float*)ws;              ws += sizeof(float) * NN;
    int*   cnt_i           = (int*)ws;                ws += sizeof(int) * NN;
    int*   cursor          = (int*)ws;                ws += sizeof(int) * NN;
    int*   rowptr          = (int*)ws;                ws += sizeof(int) * (NN + 1);
    int*   bsum            = (int*)ws;                ws += sizeof(int) * (NB_SCAN + 8);
    float* sums            = (float*)ws;              ws += sizeof(float) * NG * DIM;
    float* cntf            = (float*)ws;

    const int TB = 256;
    int nblk_n = (NN + TB - 1) / TB;
    int nblk_e = (NE + TB - 1) / TB;

    // degree + histogram (fused edge pass)
    k_init<<<nblk_n, TB, 0, stream>>>(dinv, cnt_i, NN);
    k_edge_pass<<<nblk_e, TB, 0, stream>>>(col, ew, dinv, cnt_i, NE);
    k_dinv<<<nblk_n, TB, 0, stream>>>(dinv, NN);

    // CSR build
    k_scan_reduce<<<NB_SCAN, 256, 0, stream>>>(cnt_i, bsum, NN);
    k_scan_bsums<<<1, 64, 0, stream>>>(bsum, NB_SCAN, rowptr, NN, NE);
    k_scan_final<<<NB_SCAN, 256, 0, stream>>>(cnt_i, bsum, rowptr, cursor, NN);
    k_place<<<nblk_e, TB, 0, stream>>>(row, col, ew, dinv, cursor, csr, NE);

    int gemm_blocks = (NN + 15) / 16;
    int gath_blocks = (NN + 3) / 4;

    // layer 0: x @ W0 -> H(bf16); gather -> O(f32)
    k_gemm64<false><<<gemm_blocks, 256, 0, stream>>>(x, W0, H, NN);
    k_gather<<<gath_blocks, 256, 0, stream>>>(rowptr, csr, H, dinv, b0, O, NN);

    // layer 1
    k_gemm64<true><<<gemm_blocks, 256, 0, stream>>>(O, W1, H, NN);
    k_gather<<<gath_blocks, 256, 0, stream>>>(rowptr, csr, H, dinv, b1, O, NN);

    // layer 2
    k_gemm64<true><<<gemm_blocks, 256, 0, stream>>>(O, W2, H, NN);
    k_gather<<<gath_blocks, 256, 0, stream>>>(rowptr, csr, H, dinv, b2, O, NN);

    // pooling + head
    k_pool_init<<<(NG * DIM + TB - 1) / TB, TB, 0, stream>>>(sums, cntf);
    k_pool<<<(NN + PCH - 1) / PCH, 256, 0, stream>>>(batch, O, sums, cntf, NN);
    k_head<<<NG, 64, 0, stream>>>(sums, cntf, fc1w, fc1b, fc2w, fc2b, ow, ob, out);
}

// Round 4
// 539.736 us; speedup vs baseline: 8.9218x; 1.3921x over previous
//
#include <hip/hip_runtime.h>
#include <hip/hip_bf16.h>

#define NN 100000
#define NE 1600000
#define DIM 64
#define NG 64

#define SCAN_CHUNK 1024
#define NB_SCAN ((NN + SCAN_CHUNK - 1) / SCAN_CHUNK)

static __device__ __forceinline__ unsigned short bf16bits(float v) {
    __hip_bfloat16 b = __float2bfloat16(v);
    return *reinterpret_cast<unsigned short*>(&b);
}

// ---------------- init packed deg/cnt accumulator ----------------
__global__ void k_init_packed(unsigned long long* packed, int n) {
    int i = blockIdx.x * blockDim.x + threadIdx.x;
    if (i < n) packed[i] = 0ULL;
}

// one 64-bit atomic per edge: bits 40..63 = count, bits 0..39 = sum(ew * 2^24)
__global__ void k_edge_pass(const int* __restrict__ col, const float* __restrict__ ew,
                            unsigned long long* packed, int E) {
    int e = blockIdx.x * blockDim.x + threadIdx.x;
    if (e < E) {
        unsigned int fx = (unsigned int)__float2uint_rn(ew[e] * 16777216.0f);
        unsigned long long v = (1ULL << 40) | (unsigned long long)fx;
        atomicAdd(&packed[col[e]], v);
    }
}

// decode: dinv = rsqrt(1 + fixsum*2^-24), cnt
__global__ void k_decode(const unsigned long long* __restrict__ packed,
                         float* __restrict__ dinv, int* __restrict__ cnt, int n) {
    int i = blockIdx.x * blockDim.x + threadIdx.x;
    if (i < n) {
        unsigned long long v = packed[i];
        cnt[i] = (int)(v >> 40);
        float deg = 1.0f + (float)(v & 0xFFFFFFFFFFULL) * (1.0f / 16777216.0f);
        dinv[i] = rsqrtf(deg);
    }
}

// ---------------- CSR build: scan ----------------
__global__ __launch_bounds__(256) void k_scan_reduce(const int* __restrict__ cnt,
                                                     int* __restrict__ bsum, int n) {
    __shared__ int sm[256];
    int t = threadIdx.x;
    int base = blockIdx.x * SCAN_CHUNK + t * 4;
    int s = 0;
#pragma unroll
    for (int i = 0; i < 4; ++i) {
        int idx = base + i;
        if (idx < n) s += cnt[idx];
    }
    sm[t] = s;
    __syncthreads();
    for (int off = 128; off; off >>= 1) {
        if (t < off) sm[t] += sm[t + off];
        __syncthreads();
    }
    if (t == 0) bsum[blockIdx.x] = sm[0];
}

__global__ void k_scan_bsums(int* bsum, int nb, int* rowptr, int n, int E) {
    if (threadIdx.x == 0 && blockIdx.x == 0) {
        int acc = 0;
        for (int i = 0; i < nb; ++i) {
            int v = bsum[i];
            bsum[i] = acc;
            acc += v;
        }
        rowptr[n] = E;
    }
}

__global__ __launch_bounds__(256) void k_scan_final(const int* __restrict__ cnt,
                                                    const int* __restrict__ bsum,
                                                    int* __restrict__ rowptr,
                                                    int* __restrict__ cursor, int n) {
    __shared__ int sm[256];
    int t = threadIdx.x;
    int base = blockIdx.x * SCAN_CHUNK + t * 4;
    int v[4];
    int s = 0;
#pragma unroll
    for (int i = 0; i < 4; ++i) {
        int idx = base + i;
        v[i] = (idx < n) ? cnt[idx] : 0;
        s += v[i];
    }
    sm[t] = s;
    __syncthreads();
    for (int off = 1; off < 256; off <<= 1) {
        int tmp = (t >= off) ? sm[t - off] : 0;
        __syncthreads();
        sm[t] += tmp;
        __syncthreads();
    }
    int run = bsum[blockIdx.x] + sm[t] - s;
#pragma unroll
    for (int i = 0; i < 4; ++i) {
        int idx = base + i;
        if (idx < n) {
            rowptr[idx] = run;
            cursor[idx] = run;
            run += v[i];
        }
    }
}

// csr record: .x = src row, .y = norm as float bits
__global__ void k_place(const int* __restrict__ row, const int* __restrict__ col,
                        const float* __restrict__ ew, const float* __restrict__ dinv,
                        int* cursor, int2* __restrict__ csr, int E) {
    int e = blockIdx.x * blockDim.x + threadIdx.x;
    if (e >= E) return;
    int r = row[e], c = col[e];
    int p = atomicAdd(&cursor[c], 1);
    float nm = dinv[r] * ew[e] * dinv[c];
    csr[p] = make_int2(r, __float_as_int(nm));
}

// ---------------- cast x -> bf16 ----------------
__global__ void k_cast(const float* __restrict__ x, unsigned short* __restrict__ xb, int nq) {
    int i = blockIdx.x * blockDim.x + threadIdx.x;  // one float4 each
    if (i >= nq) return;
    float4 v = ((const float4*)x)[i];
    ushort4 o;
    o.x = bf16bits(v.x);
    o.y = bf16bits(v.y);
    o.z = bf16bits(v.z);
    o.w = bf16bits(v.w);
    ((ushort4*)xb)[i] = o;
}

// ---------------- gather: out = h[node]*dinv^2 + sum_e h[src]*nrm (h in bf16) ----
__global__ __launch_bounds__(256) void k_gather(const int* __restrict__ rowptr,
                                                const int2* __restrict__ csr,
                                                const __hip_bfloat16* __restrict__ h,
                                                const float* __restrict__ dinv,
                                                float* __restrict__ out, int n) {
    int node = blockIdx.x * 4 + (threadIdx.x >> 6);
    if (node >= n) return;
    int d = threadIdx.x & 63;
    int e = rowptr[node], end = rowptr[node + 1];
    float di = dinv[node];
    float acc = __bfloat162float(h[(size_t)node * DIM + d]) * (di * di);
    // 8-deep unroll: 8 independent row loads in flight per wave
    for (; e + 8 <= end; e += 8) {
        int2 p[8];
#pragma unroll
        for (int i = 0; i < 8; ++i) p[i] = csr[e + i];
        float hv[8];
#pragma unroll
        for (int i = 0; i < 8; ++i) hv[i] = __bfloat162float(h[(size_t)p[i].x * DIM + d]);
#pragma unroll
        for (int i = 0; i < 8; ++i) acc = fmaf(hv[i], __int_as_float(p[i].y), acc);
    }
    for (; e < end; ++e) {
        int2 p = csr[e];
        acc = fmaf(__bfloat162float(h[(size_t)p.x * DIM + d]), __int_as_float(p.y), acc);
    }
    out[(size_t)node * DIM + d] = acc;
}

// ---------------- GEMM: out_bf16[n][64] = relu(in[n][64] @ W + b) ----------------
__global__ __launch_bounds__(256) void k_gemm64(const float* __restrict__ in,
                                                const float* __restrict__ W,
                                                const float* __restrict__ b,
                                                __hip_bfloat16* __restrict__ out, int n) {
    __shared__ float sW[64][64];
    __shared__ float sX[16][64];
    int tid = threadIdx.x;
    // vectorized staging: W = 1024 float4 (4/thread), X tile = 256 float4 (1/thread)
#pragma unroll
    for (int i = 0; i < 4; ++i) {
        int q = tid + i * 256;                 // float4 index into W
        ((float4*)&sW[0][0])[q] = ((const float4*)W)[q];
    }
    int base = blockIdx.x * 16;
    {
        int r = tid >> 4, cq = tid & 15;       // 16 float4 per row
        int node = base + r;
        float4 v = (node < n) ? ((const float4*)in)[(size_t)node * 16 + cq]
                              : make_float4(0.f, 0.f, 0.f, 0.f);
        ((float4*)&sX[r][0])[cq] = v;
    }
    __syncthreads();
    int d = tid & 63;
    int r0 = (tid >> 6) * 4;
    float a0 = 0.f, a1 = 0.f, a2 = 0.f, a3 = 0.f;
#pragma unroll
    for (int k = 0; k < 64; ++k) {
        float w = sW[k][d];
        a0 = fmaf(sX[r0 + 0][k], w, a0);
        a1 = fmaf(sX[r0 + 1][k], w, a1);
        a2 = fmaf(sX[r0 + 2][k], w, a2);
        a3 = fmaf(sX[r0 + 3][k], w, a3);
    }
    float bv = b[d];
    a0 = fmaxf(a0 + bv, 0.f);
    a1 = fmaxf(a1 + bv, 0.f);
    a2 = fmaxf(a2 + bv, 0.f);
    a3 = fmaxf(a3 + bv, 0.f);
    if (base + r0 + 0 < n) out[(size_t)(base + r0 + 0) * DIM + d] = __float2bfloat16(a0);
    if (base + r0 + 1 < n) out[(size_t)(base + r0 + 1) * DIM + d] = __float2bfloat16(a1);
    if (base + r0 + 2 < n) out[(size_t)(base + r0 + 2) * DIM + d] = __float2bfloat16(a2);
    if (base + r0 + 3 < n) out[(size_t)(base + r0 + 3) * DIM + d] = __float2bfloat16(a3);
}

// ---------------- pooling (batch sorted -> run-length partial sums) ----------
__global__ void k_pool_init(float* sums, float* cnt) {
    int i = blockIdx.x * blockDim.x + threadIdx.x;
    if (i < NG * DIM) sums[i] = 0.0f;
    if (i < NG) cnt[i] = 0.0f;
}

#define PCH 256
__global__ __launch_bounds__(256) void k_pool(const int* __restrict__ batch,
                                              const float* __restrict__ h,
                                              float* sums, float* cnt, int n) {
    int t = threadIdx.x;
    int d = t & 63, s = t >> 6;
    int base = blockIdx.x * PCH;
    float acc = 0.f;
    int gcur = -1, cntv = 0;
    for (int i = s; i < PCH; i += 4) {
        int node = base + i;
        if (node >= n) break;
        int g = batch[node];
        if (g != gcur) {
            if (gcur >= 0) {
                atomicAdd(&sums[gcur * DIM + d], acc);
                if (d == 0) atomicAdd(&cnt[gcur], (float)cntv);
            }
            gcur = g;
            acc = 0.f;
            cntv = 0;
        }
        acc += h[(size_t)node * DIM + d];
        cntv++;
    }
    if (gcur >= 0) {
        atomicAdd(&sums[gcur * DIM + d], acc);
        if (d == 0) atomicAdd(&cnt[gcur], (float)cntv);
    }
}

// ---------------- head: mean -> @W2+b2 -> fc1 relu -> fc2 -> out ----------------
__global__ __launch_bounds__(64) void k_head(const float* __restrict__ sums,
                                             const float* __restrict__ cnt,
                                             const float* __restrict__ W2,
                                             const float* __restrict__ b2,
                                             const float* __restrict__ fc1w,
                                             const float* __restrict__ fc1b,
                                             const float* __restrict__ fc2w,
                                             const float* __restrict__ fc2b,
                                             const float* __restrict__ ow,
                                             const float* __restrict__ ob,
                                             float* __restrict__ out) {
    int g = blockIdx.x;
    int t = threadIdx.x;
    __shared__ float gv[64];
    __shared__ float tv[64];
    float c = fmaxf(cnt[g], 1.0f);
    gv[t] = sums[g * DIM + t] / c;
    __syncthreads();
    // layer-2 GEMM folded here: t2 = mean @ W2 + b2 (no relu)
    float acc2 = b2[t];
#pragma unroll
    for (int k = 0; k < 64; ++k) acc2 = fmaf(gv[k], W2[k * 64 + t], acc2);
    tv[t] = acc2;
    __syncthreads();
    float r = 0.0f;
    if (t < 32) {
        float acc = fc1b[t];
#pragma unroll
        for (int k = 0; k < 64; ++k) acc = fmaf(tv[k], fc1w[k * 32 + t], acc);
        acc = fmaxf(acc, 0.0f);
        r = acc * fc2w[t];
    }
#pragma unroll
    for (int off = 16; off; off >>= 1) r += __shfl_down(r, off);
    if (t == 0) out[g] = (r + fc2b[0]) * ow[0] + ob[0];
}

extern "C" void kernel_launch(void* const* d_in, const int* in_sizes, int n_in,
                              void* d_out, int out_size, void* d_ws, size_t ws_size,
                              hipStream_t stream) {
    const float* x   = (const float*)d_in[0];
    const int* eidx  = (const int*)d_in[1];
    const float* ew  = (const float*)d_in[2];
    const int* batch = (const int*)d_in[3];
    const float* W0  = (const float*)d_in[4];
    const float* b0  = (const float*)d_in[5];
    const float* W1  = (const float*)d_in[6];
    const float* b1  = (const float*)d_in[7];
    const float* W2  = (const float*)d_in[8];
    const float* b2  = (const float*)d_in[9];
    const float* fc1w = (const float*)d_in[10];
    const float* fc1b = (const float*)d_in[11];
    const float* fc2w = (const float*)d_in[12];
    const float* fc2b = (const float*)d_in[13];
    const float* ow   = (const float*)d_in[14];
    const float* ob   = (const float*)d_in[15];
    float* out = (float*)d_out;

    const int* row = eidx;
    const int* col = eidx + NE;

    // workspace layout (8B-aligned blocks first)
    char* ws = (char*)d_ws;
    unsigned long long* packed = (unsigned long long*)ws;  ws += sizeof(unsigned long long) * NN;
    int2* csr              = (int2*)ws;               ws += sizeof(int2) * NE;                 // 12.8MB
    float* G               = (float*)ws;              ws += sizeof(float) * (size_t)NN * DIM;  // 25.6MB
    __hip_bfloat16* Xb     = (__hip_bfloat16*)ws;     ws += sizeof(__hip_bfloat16) * (size_t)NN * DIM;  // 12.8MB
    float* dinv            = (float*)ws;              ws += sizeof(float) * NN;
    int*   cnt_i           = (int*)ws;                ws += sizeof(int) * NN;
    int*   cursor          = (int*)ws;                ws += sizeof(int) * NN;
    int*   rowptr          = (int*)ws;                ws += sizeof(int) * (NN + 1);
    int*   bsum            = (int*)ws;                ws += sizeof(int) * (NB_SCAN + 8);
    float* sums            = (float*)ws;              ws += sizeof(float) * NG * DIM;
    float* cntf            = (float*)ws;

    const int TB = 256;
    int nblk_n = (NN + TB - 1) / TB;
    int nblk_e = (NE + TB - 1) / TB;

    // degree + histogram in ONE 64-bit atomic per edge
    k_init_packed<<<nblk_n, TB, 0, stream>>>(packed, NN);
    k_edge_pass<<<nblk_e, TB, 0, stream>>>(col, ew, packed, NE);
    k_decode<<<nblk_n, TB, 0, stream>>>(packed, dinv, cnt_i, NN);

    // CSR build
    k_scan_reduce<<<NB_SCAN, 256, 0, stream>>>(cnt_i, bsum, NN);
    k_scan_bsums<<<1, 64, 0, stream>>>(bsum, NB_SCAN, rowptr, NN, NE);
    k_scan_final<<<NB_SCAN, 256, 0, stream>>>(cnt_i, bsum, rowptr, cursor, NN);
    k_place<<<nblk_e, TB, 0, stream>>>(row, col, ew, dinv, cursor, csr, NE);

    // cast x -> bf16
    int nq = NN * DIM / 4;
    k_cast<<<(nq + TB - 1) / TB, TB, 0, stream>>>(x, (unsigned short*)Xb, nq);

    int gemm_blocks = (NN + 15) / 16;
    int gath_blocks = (NN + 3) / 4;

    // gather-first: g = A_hat @ X ; X' = relu(g @ W + b)
    k_gather<<<gath_blocks, 256, 0, stream>>>(rowptr, csr, Xb, dinv, G, NN);
    k_gemm64<<<gemm_blocks, 256, 0, stream>>>(G, W0, b0, Xb, NN);
    k_gather<<<gath_blocks, 256, 0, stream>>>(rowptr, csr, Xb, dinv, G, NN);
    k_gemm64<<<gemm_blocks, 256, 0, stream>>>(G, W1, b1, Xb, NN);
    k_gather<<<gath_blocks, 256, 0, stream>>>(rowptr, csr, Xb, dinv, G, NN);

    // pool over g2; W2/b2 folded into head
    k_pool_init<<<(NG * DIM + TB - 1) / TB, TB, 0, stream>>>(sums, cntf);
    k_pool<<<(NN + PCH - 1) / PCH, 256, 0, stream>>>(batch, G, sums, cntf, NN);
    k_head<<<NG, 64, 0, stream>>>(sums, cntf, W2, b2, fc1w, fc1b, fc2w, fc2b, ow, ob, out);
}